// Round 14
// baseline (736.862 us; speedup 1.0000x reference)
//
#include <hip/hip_runtime.h>
#include <hip/hip_fp16.h>
#include <math.h>

typedef _Float16 f16x8 __attribute__((ext_vector_type(8)));
typedef _Float16 f16x2 __attribute__((ext_vector_type(2)));
typedef float f32x4 __attribute__((ext_vector_type(4)));

union U4H8 { uint4 u; f16x8 h; };
union U4D2 { uint4 u; f16x2 d2[4]; unsigned w[4]; };

// acc += f16_lo(pk) * s   /   acc += f16_hi(pk) * s   (single VALU op, f32 accumulate)
__device__ __forceinline__ float fmamix_lo(unsigned pk, float s, float acc) {
    asm("v_fma_mix_f32 %0, %1, %2, %0 op_sel:[0,0,0] op_sel_hi:[1,0,0]"
        : "+v"(acc) : "v"(pk), "v"(s));
    return acc;
}
__device__ __forceinline__ float fmamix_hi(unsigned pk, float s, float acc) {
    asm("v_fma_mix_f32 %0, %1, %2, %0 op_sel:[1,0,0] op_sel_hi:[1,0,0]"
        : "+v"(acc) : "v"(pk), "v"(s));
    return acc;
}
__device__ __forceinline__ float fdot2(f16x2 a, f16x2 b, float c) {
#if __has_builtin(__builtin_amdgcn_fdot2)
    return __builtin_amdgcn_fdot2(a, b, c, false);
#else
    asm("v_dot2_f32_f16 %0, %1, %2, %0" : "+v"(c) : "v"(a), "v"(b));
    return c;
#endif
}

__device__ __forceinline__ void unpack8(uint4 u, float* f) {
    union { uint4 u; __half2 h2[4]; } U; U.u = u;
    float2 a = __half22float2(U.h2[0]);
    float2 b = __half22float2(U.h2[1]);
    float2 c = __half22float2(U.h2[2]);
    float2 d = __half22float2(U.h2[3]);
    f[0] = a.x; f[1] = a.y; f[2] = b.x; f[3] = b.y;
    f[4] = c.x; f[5] = c.y; f[6] = d.x; f[7] = d.y;
}

// ---------- preprocessing ----------
__global__ void k_zero(int* p, int n) {
    int i = blockIdx.x * blockDim.x + threadIdx.x;
    if (i < n) p[i] = 0;
}

// 4-way multi-buffered count: edge i uses copy (i&3); rank within copy
__global__ void k_count(const int* __restrict__ dst, int* deg4, int* rank, int E, int N) {
    int i = blockIdx.x * blockDim.x + threadIdx.x;
    if (i < E) rank[i] = atomicAdd(&deg4[(i & 3) * N + dst[i]], 1);
}

// deg_tot + dis (fused)
__global__ void k_meta_pre(const int* __restrict__ deg4, int* deg, float* dis, int N) {
    int n = blockIdx.x * blockDim.x + threadIdx.x;
    if (n >= N) return;
    int d = deg4[n] + deg4[N + n] + deg4[2 * N + n] + deg4[3 * N + n];
    deg[n] = d;
    dis[n] = rsqrtf((float)(d + 1));  // +1 self loop
}

// meta[n] = { offs[n]+1, b1, b2, b3 } where b_c = prefix of copy counts
__global__ void k_meta_post(const int* __restrict__ deg4, const int* __restrict__ offs,
                            int4* meta, int N) {
    int n = blockIdx.x * blockDim.x + threadIdx.x;
    if (n >= N) return;
    int d0 = deg4[n], d1 = deg4[N + n], d2 = deg4[2 * N + n];
    meta[n] = make_int4(offs[n] + 1, d0, d0 + d1, d0 + d1 + d2);
}

__global__ void k_scan1(const int* __restrict__ deg, int* part, int N) {
    int base = blockIdx.x * 1024;
    int tid = threadIdx.x;
    int s = 0;
#pragma unroll
    for (int j = 0; j < 4; ++j) {
        int idx = base + tid * 4 + j;
        if (idx < N) s += deg[idx] + 1;
    }
    __shared__ int sm[256];
    sm[tid] = s;
    __syncthreads();
    for (int off = 128; off > 0; off >>= 1) {
        if (tid < off) sm[tid] += sm[tid + off];
        __syncthreads();
    }
    if (tid == 0) part[blockIdx.x] = sm[0];
}

__global__ void k_scan2(int* part, int nb, int* offs, int N) {
    if (blockIdx.x == 0 && threadIdx.x == 0) {
        int run = 0;
        for (int b = 0; b < nb; ++b) { int t = part[b]; part[b] = run; run += t; }
        offs[N] = run;
    }
}

__global__ void k_scan3(const int* __restrict__ deg, const int* __restrict__ part,
                        int* offs, int N) {
    __shared__ int sm[256];
    int base = blockIdx.x * 1024;
    int tid = threadIdx.x;
    int a[4];
    int s = 0;
#pragma unroll
    for (int j = 0; j < 4; ++j) {
        int idx = base + tid * 4 + j;
        a[j] = (idx < N) ? (deg[idx] + 1) : 0;
        s += a[j];
    }
    sm[tid] = s;
    __syncthreads();
    for (int off = 1; off < 256; off <<= 1) {
        int v = (tid >= off) ? sm[tid - off] : 0;
        __syncthreads();
        sm[tid] += v;
        __syncthreads();
    }
    int excl = sm[tid] - s + part[blockIdx.x];
#pragma unroll
    for (int j = 0; j < 4; ++j) {
        int idx = base + tid * 4 + j;
        if (idx < N) offs[idx] = excl;
        excl += a[j];
    }
}

// atomic-free fill: edge i -> csr[meta.x + base_c + rank]; tail adds self-loops at meta.x-1
__global__ void k_fill(const int* __restrict__ ei, int E, int N,
                       const int4* __restrict__ meta,
                       const int* __restrict__ rank, int* csr) {
    int i = blockIdx.x * blockDim.x + threadIdx.x;
    if (i < E) {
        int s = ei[i], d = ei[E + i];
        int c = i & 3;
        int4 m = meta[d];
        int base = (c == 0) ? 0 : ((c == 1) ? m.y : ((c == 2) ? m.z : m.w));
        csr[m.x + base + rank[i]] = s;
    } else if (i < E + N) {
        int n = i - E;
        csr[meta[n].x - 1] = n;
    }
}

__global__ void k_gstart(const int* __restrict__ batch, int N, int* gstart, int G) {
    int g = blockIdx.x * blockDim.x + threadIdx.x;
    if (g > G) return;
    int lo = 0, hi = N;
    while (lo < hi) {
        int mid = (lo + hi) >> 1;
        if (batch[mid] < g) lo = mid + 1; else hi = mid;
    }
    gstart[g] = lo;
}

// ---------- pre-scaled cast: g0 = fp16(dis * x) ----------
__global__ __launch_bounds__(256) void k_cast(
    const float* __restrict__ x, const float* __restrict__ dis,
    __half* __restrict__ hx, int npairs)
{
    int i = blockIdx.x * blockDim.x + threadIdx.x;
    if (i >= npairs) return;
    float2 v = ((const float2*)x)[i];
    float d = dis[i >> 6];
    ((__half2*)hx)[i] = __floats2half2_rn(d * v.x, d * v.y);
}

// ---------- W prep: split W = hi + lo (fp16) transposed, packed in MFMA frag order ----
__global__ void k_prepw(const float* __restrict__ W, __half* __restrict__ wt_hi,
                        __half* __restrict__ wt_lo) {
    int t = blockIdx.x * 256 + threadIdx.x;   // 0..16383
    int j = t & 7, q = t >> 3;
    int l15 = q & 15, nt = (q >> 4) & 7;
    int lg = (q >> 7) & 3, ks = q >> 9;
    int n = nt * 16 + l15, k = ks * 32 + lg * 8 + j;
    float w = W[k * 128 + n];
    __half hi = __float2half_rn(w);
    wt_hi[t] = hi;
    wt_lo[t] = __float2half_rn(w - __half2float(hi));
}

// ---------- FUSED GCN layer: per-tile edge-gather aggregation + MFMA GEMM ----------
// B-fragment for row l15 is built in-register by lanes (l15, lg=0..3):
// lane accumulates feature chunks (ks*4+lg)*8..+7 over edges of node l15.
#define GEMM_STG_OFF 65536
#define GEMM_STG_STRIDE 72
#define GEMM_LDS_BYTES (65536 + 8 * 16 * GEMM_STG_STRIDE)

__global__ __launch_bounds__(512) void k_gcn_fused(
    const __half* __restrict__ h, const int* __restrict__ csr,
    const int* __restrict__ offs, const float* __restrict__ dis,
    const __half* __restrict__ wt_hi, const __half* __restrict__ wt_lo,
    const float* __restrict__ bias, const float* __restrict__ scale,
    __half* __restrict__ out, int ntiles, int nrows, float* __restrict__ invn_out)
{
    extern __shared__ char smem[];
    uint4* wlds = (uint4*)smem;
    int tid = threadIdx.x;
    int wv = tid >> 6;
    char* stg = smem + GEMM_STG_OFF + wv * 16 * GEMM_STG_STRIDE;

    {
        const uint4* sh = (const uint4*)wt_hi;
        const uint4* sl = (const uint4*)wt_lo;
        for (int t = tid; t < 2048; t += 512) {
            wlds[t] = sh[t];
            wlds[t + 2048] = sl[t];
        }
    }
    __syncthreads();

    int lane = tid & 63;
    int l15 = lane & 15, lg = lane >> 4;
    const uint4* h4 = (const uint4*)h;
    float one = 1.0f;

    f32x4 bv[8];
#pragma unroll
    for (int nt = 0; nt < 8; ++nt)
        bv[nt] = *(const f32x4*)(bias + nt * 16 + lg * 4);

    int wid = blockIdx.x * 8 + wv;
    int t0 = wid * 2;
    for (int tile = t0; tile < t0 + 2 && tile < ntiles; ++tile) {
        int row0 = tile * 16;
        int row = row0 + l15;
        if (row >= nrows) row = nrows - 1;

        // ---- in-register aggregation: 32 f32 accumulators per lane ----
        float ag[32];
#pragma unroll
        for (int i = 0; i < 32; ++i) ag[i] = 0.f;
        int j0 = offs[row], j1 = offs[row + 1];
        int j = j0;
        for (; j + 2 <= j1; j += 2) {
            int s0 = csr[j], s1 = csr[j + 1];
            U4D2 c0[4], c1[4];
#pragma unroll
            for (int ks = 0; ks < 4; ++ks) c0[ks].u = h4[(unsigned)(s0 * 16 + ks * 4 + lg)];
#pragma unroll
            for (int ks = 0; ks < 4; ++ks) c1[ks].u = h4[(unsigned)(s1 * 16 + ks * 4 + lg)];
#pragma unroll
            for (int ks = 0; ks < 4; ++ks)
#pragma unroll
                for (int w = 0; w < 4; ++w) {
                    ag[ks * 8 + 2 * w]     = fmamix_lo(c0[ks].w[w], one, ag[ks * 8 + 2 * w]);
                    ag[ks * 8 + 2 * w + 1] = fmamix_hi(c0[ks].w[w], one, ag[ks * 8 + 2 * w + 1]);
                    ag[ks * 8 + 2 * w]     = fmamix_lo(c1[ks].w[w], one, ag[ks * 8 + 2 * w]);
                    ag[ks * 8 + 2 * w + 1] = fmamix_hi(c1[ks].w[w], one, ag[ks * 8 + 2 * w + 1]);
                }
        }
        for (; j < j1; ++j) {
            int s = csr[j];
            U4D2 c[4];
#pragma unroll
            for (int ks = 0; ks < 4; ++ks) c[ks].u = h4[(unsigned)(s * 16 + ks * 4 + lg)];
#pragma unroll
            for (int ks = 0; ks < 4; ++ks)
#pragma unroll
                for (int w = 0; w < 4; ++w) {
                    ag[ks * 8 + 2 * w]     = fmamix_lo(c[ks].w[w], one, ag[ks * 8 + 2 * w]);
                    ag[ks * 8 + 2 * w + 1] = fmamix_hi(c[ks].w[w], one, ag[ks * 8 + 2 * w + 1]);
                }
        }
        // pack to f16 B-fragments, scaled by dis[row]
        float dd = dis[row];
        U4H8 b[4];
#pragma unroll
        for (int ks = 0; ks < 4; ++ks) {
            union { uint4 u; __half2 h2[4]; } P;
#pragma unroll
            for (int w = 0; w < 4; ++w)
                P.h2[w] = __floats2half2_rn(dd * ag[ks * 8 + 2 * w], dd * ag[ks * 8 + 2 * w + 1]);
            b[ks].u = P.u;
        }

        // ---- MFMA: out^T-tile = W^T(hi+lo) · b ----
        f32x4 acc[8];
#pragma unroll
        for (int nt = 0; nt < 8; ++nt) acc[nt] = (f32x4){0.f, 0.f, 0.f, 0.f};
#pragma unroll
        for (int ks = 0; ks < 4; ++ks) {
#pragma unroll
            for (int nt = 0; nt < 8; ++nt) {
                int fi = (ks * 4 + lg) * 128 + nt * 16 + l15;
                U4H8 ah; ah.u = wlds[fi];
                U4H8 al; al.u = wlds[fi + 2048];
                acc[nt] = __builtin_amdgcn_mfma_f32_16x16x32_f16(ah.h, b[ks].h, acc[nt], 0, 0, 0);
                acc[nt] = __builtin_amdgcn_mfma_f32_16x16x32_f16(al.h, b[ks].h, acc[nt], 0, 0, 0);
            }
        }

        // ---- epilogue: bias + tanh (+scale) staged through LDS, full-line stores ----
        float sc = scale ? scale[row] : 1.0f;
        float sq = 0.f;
        int node = lane >> 2, sub = lane & 3;
#pragma unroll
        for (int np = 0; np < 4; ++np) {
#pragma unroll
            for (int hh = 0; hh < 2; ++hh) {
                int nt = np * 2 + hh;
                float o[4];
#pragma unroll
                for (int r = 0; r < 4; ++r) {
                    float xv = acc[nt][r] + bv[nt][r];
                    float e = __expf(xv + xv);        // tanh(x) = 1 - 2/(e^{2x}+1)
                    o[r] = 1.f - 2.f / (e + 1.f);
                    sq += o[r] * o[r];
                }
                union { __half2 h2[2]; uint2 u; } pk;
                pk.h2[0] = __floats2half2_rn(sc * o[0], sc * o[1]);
                pk.h2[1] = __floats2half2_rn(sc * o[2], sc * o[3]);
                *(uint2*)(stg + l15 * GEMM_STG_STRIDE + hh * 32 + lg * 8) = pk.u;
            }
            uint4 v = *(const uint4*)(stg + node * GEMM_STG_STRIDE + sub * 16);
            if (row0 + node < nrows)
                *(uint4*)(out + (size_t)(row0 + node) * 128 + np * 32 + sub * 8) = v;
        }
        if (invn_out) {
            sq += __shfl_xor(sq, 16, 64);
            sq += __shfl_xor(sq, 32, 64);
            if (lg == 0) invn_out[row] = 1.0f / fmaxf(sqrtf(sq), 1e-12f);
        }
    }
}

// ---------- AGNN layer: 16 lanes/node, 4-deep gather pipeline, fdot2 + fma_mix ------
__global__ __launch_bounds__(256) void k_agnn(
    const __half* __restrict__ h, const int* __restrict__ csr,
    const int* __restrict__ offs, const float* __restrict__ invn,
    const float* __restrict__ beta_p, __half* __restrict__ out, int N,
    float* __restrict__ invn_out)
{
    int node = (blockIdx.x * blockDim.x + threadIdx.x) >> 4;
    int l = threadIdx.x & 15;
    if (node >= N) return;
    int j0 = offs[node], j1 = offs[node + 1];
    const uint4* h4 = (const uint4*)h;
    U4D2 D; D.u = h4[(unsigned)(node * 16 + l)];
    float bi = beta_p[0] * invn[node];
    float denom = 0.f;
    float acc[8] = {0.f, 0.f, 0.f, 0.f, 0.f, 0.f, 0.f, 0.f};
    int j = j0;
    for (; j + 4 <= j1; j += 4) {
        U4D2 A[4];
        float in_[4];
#pragma unroll
        for (int e = 0; e < 4; ++e) {
            int s = csr[j + e];
            in_[e] = invn[s];
            A[e].u = h4[(unsigned)(s * 16 + l)];
        }
        float d[4] = {0.f, 0.f, 0.f, 0.f};
#pragma unroll
        for (int e = 0; e < 4; ++e)
#pragma unroll
            for (int k = 0; k < 4; ++k) d[e] = fdot2(A[e].d2[k], D.d2[k], d[e]);
#pragma unroll
        for (int off = 1; off < 16; off <<= 1) {
            d[0] += __shfl_xor(d[0], off, 64);
            d[1] += __shfl_xor(d[1], off, 64);
            d[2] += __shfl_xor(d[2], off, 64);
            d[3] += __shfl_xor(d[3], off, 64);
        }
        float p[4];
#pragma unroll
        for (int e = 0; e < 4; ++e) {
            p[e] = __expf(bi * in_[e] * d[e]);
            denom += p[e];
        }
#pragma unroll
        for (int e = 0; e < 4; ++e)
#pragma unroll
            for (int k = 0; k < 4; ++k) {
                acc[2 * k]     = fmamix_lo(A[e].w[k], p[e], acc[2 * k]);
                acc[2 * k + 1] = fmamix_hi(A[e].w[k], p[e], acc[2 * k + 1]);
            }
    }
    for (; j < j1; ++j) {
        int s = csr[j];
        float ins = invn[s];
        U4D2 A; A.u = h4[(unsigned)(s * 16 + l)];
        float d = 0.f;
#pragma unroll
        for (int k = 0; k < 4; ++k) d = fdot2(A.d2[k], D.d2[k], d);
#pragma unroll
        for (int off = 1; off < 16; off <<= 1) d += __shfl_xor(d, off, 64);
        float p = __expf(bi * ins * d);
        denom += p;
#pragma unroll
        for (int k = 0; k < 4; ++k) {
            acc[2 * k]     = fmamix_lo(A.w[k], p, acc[2 * k]);
            acc[2 * k + 1] = fmamix_hi(A.w[k], p, acc[2 * k + 1]);
        }
    }
    float inv = 1.0f / denom;
    float o[8];
#pragma unroll
    for (int i = 0; i < 8; ++i) o[i] = tanhf(acc[i] * inv);
    union { uint4 u; __half2 h2[4]; } P;
    P.h2[0] = __floats2half2_rn(o[0], o[1]);
    P.h2[1] = __floats2half2_rn(o[2], o[3]);
    P.h2[2] = __floats2half2_rn(o[4], o[5]);
    P.h2[3] = __floats2half2_rn(o[6], o[7]);
    ((uint4*)out)[(unsigned)(node * 16 + l)] = P.u;
    if (invn_out) {
        float s2 = 0.f;
#pragma unroll
        for (int i = 0; i < 8; ++i) s2 += o[i] * o[i];
#pragma unroll
        for (int off = 1; off < 16; off <<= 1) s2 += __shfl_xor(s2, off, 64);
        if (l == 0) invn_out[node] = 1.0f / fmaxf(sqrtf(s2), 1e-12f);
    }
}

// ---------- per-graph mean pool + layernorm + final linear (16 lanes/graph) ----------
__global__ __launch_bounds__(256) void k_pool(
    const __half* __restrict__ h, const int* __restrict__ gstart,
    const float* __restrict__ Wl, const float* __restrict__ bl,
    float* __restrict__ out, int G)
{
    int g = (blockIdx.x * blockDim.x + threadIdx.x) >> 4;
    int l = threadIdx.x & 15;
    if (g >= G) return;
    int s = gstart[g], e = gstart[g + 1];
    const uint4* hp = (const uint4*)h + l;
    float acc[8] = {0.f, 0.f, 0.f, 0.f, 0.f, 0.f, 0.f, 0.f};
    for (int n = s; n < e; ++n) {
        float f[8]; unpack8(hp[(size_t)n * 16], f);
#pragma unroll
        for (int i = 0; i < 8; ++i) acc[i] += f[i];
    }
    float inv = 1.0f / fmaxf((float)(e - s), 1.0f);
#pragma unroll
    for (int i = 0; i < 8; ++i) acc[i] *= inv;
    float part = 0.f;
#pragma unroll
    for (int i = 0; i < 8; ++i) part += acc[i];
#pragma unroll
    for (int off = 1; off < 16; off <<= 1) part += __shfl_xor(part, off, 64);
    float mu = part * (1.0f / 128.0f);
    float vpart = 0.f;
#pragma unroll
    for (int i = 0; i < 8; ++i) { float d = acc[i] - mu; vpart += d * d; }
#pragma unroll
    for (int off = 1; off < 16; off <<= 1) vpart += __shfl_xor(vpart, off, 64);
    float r = rsqrtf(vpart * (1.0f / 128.0f) + 1e-5f);
    float4 w0 = *(const float4*)(Wl + l * 8);
    float4 w1 = *(const float4*)(Wl + l * 8 + 4);
    float wv[8] = {w0.x, w0.y, w0.z, w0.w, w1.x, w1.y, w1.z, w1.w};
    float dot = 0.f;
#pragma unroll
    for (int i = 0; i < 8; ++i) dot += (acc[i] - mu) * r * wv[i];
#pragma unroll
    for (int off = 1; off < 16; off <<= 1) dot += __shfl_xor(dot, off, 64);
    if (l == 0) out[g] = dot + bl[0];
}

extern "C" void kernel_launch(void* const* d_in, const int* in_sizes, int n_in,
                              void* d_out, int out_size, void* d_ws, size_t ws_size,
                              hipStream_t stream) {
    const float* x  = (const float*)d_in[0];
    const int* ei   = (const int*)d_in[1];      // [2][E]
    const int* batch = (const int*)d_in[2];
    const float* Ws[5] = {(const float*)d_in[3], (const float*)d_in[5],
                          (const float*)d_in[7], (const float*)d_in[9],
                          (const float*)d_in[11]};
    const float* bs[5] = {(const float*)d_in[4], (const float*)d_in[6],
                          (const float*)d_in[8], (const float*)d_in[10],
                          (const float*)d_in[12]};
    const float* beta1 = (const float*)d_in[13];
    const float* beta2 = (const float*)d_in[14];
    const float* Wl = (const float*)d_in[15];
    const float* bl = (const float*)d_in[16];
    float* out = (float*)d_out;

    int N = in_sizes[0] / 128;
    int E = in_sizes[1] / 2;
    int G = out_size;

    char* ws = (char*)d_ws;
    size_t off = 0;
    auto alloc = [&](size_t bytes) -> void* {
        void* p = ws + off;
        off = (off + bytes + 255) & ~(size_t)255;
        return p;
    };
    __half* hA   = (__half*)alloc((size_t)N * 128 * 2);
    __half* hB   = (__half*)alloc((size_t)N * 128 * 2);
    int*   deg4  = (int*)alloc((size_t)4 * N * 4);
    int*   deg   = (int*)alloc((size_t)N * 4);
    int*   offs  = (int*)alloc((size_t)(N + 1) * 4);
    int4*  meta  = (int4*)alloc((size_t)N * 16);
    int*   rank  = (int*)alloc((size_t)E * 4);
    int*   csr   = (int*)alloc((size_t)(E + N) * 4);
    float* dis   = (float*)alloc((size_t)N * 4);
    float* invn  = (float*)alloc((size_t)N * 4);
    float* invn2 = (float*)alloc((size_t)N * 4);
    __half* wtHi = (__half*)alloc((size_t)5 * 16384 * 2);
    __half* wtLo = (__half*)alloc((size_t)5 * 16384 * 2);
    int nb = (N + 1023) / 1024;
    int*   part  = (int*)alloc((size_t)nb * 4);
    int*   gst   = (int*)alloc((size_t)(G + 1) * 4);

    // CSR build (4-way multi-buffered count, atomic-free fill) + x cast + W prep
    k_zero<<<(4 * N + 255) / 256, 256, 0, stream>>>(deg4, 4 * N);
    k_count<<<(E + 255) / 256, 256, 0, stream>>>(ei + E, deg4, rank, E, N);
    k_meta_pre<<<(N + 255) / 256, 256, 0, stream>>>(deg4, deg, dis, N);
    k_scan1<<<nb, 256, 0, stream>>>(deg, part, N);
    k_scan2<<<1, 64, 0, stream>>>(part, nb, offs, N);
    k_scan3<<<nb, 256, 0, stream>>>(deg, part, offs, N);
    k_meta_post<<<(N + 255) / 256, 256, 0, stream>>>(deg4, offs, meta, N);
    k_fill<<<(E + N + 255) / 256, 256, 0, stream>>>(ei, E, N, meta, rank, csr);
    k_gstart<<<(G + 1 + 255) / 256, 256, 0, stream>>>(batch, N, gst, G);
    k_cast<<<(N * 64 + 255) / 256, 256, 0, stream>>>(x, dis, hA, N * 64);
    for (int l = 0; l < 5; ++l)
        k_prepw<<<64, 256, 0, stream>>>(Ws[l], wtHi + l * 16384, wtLo + l * 16384);

    int aggBlocks = (N + 15) / 16;   // 16 nodes per 256-thread block (AGNN)
    int ntiles = (N + 15) / 16;
    int fusedBlocks = (ntiles + 15) / 16;   // 8 waves/block, 2 tiles/wave

    // 5 fused GCN layers; layers 0-3 write dis-scaled fp16; layer 4 unscaled + invn
    const __half* hin = hA;
    __half* hout = hB;
    for (int l = 0; l < 5; ++l) {
        k_gcn_fused<<<fusedBlocks, 512, GEMM_LDS_BYTES, stream>>>(
            hin, csr, offs, dis, wtHi + l * 16384, wtLo + l * 16384, bs[l],
            (l < 4) ? dis : nullptr, hout, ntiles, N,
            (l == 4) ? invn : nullptr);
        const __half* t = hin; hin = hout; hout = (__half*)t;
    }
    // after loop: hin = h5 (hB), hout = hA
    k_agnn<<<aggBlocks, 256, 0, stream>>>(hin, csr, offs, invn, beta1, hout, N, invn2);
    k_agnn<<<aggBlocks, 256, 0, stream>>>(hout, csr, offs, invn2, beta2, (__half*)hin, N, nullptr);
    k_pool<<<(G + 15) / 16, 256, 0, stream>>>(hin, gst, Wl, bl, out, G);
}

// Round 15
// 726.684 us; speedup vs baseline: 1.0140x; 1.0140x over previous
//
#include <hip/hip_runtime.h>
#include <hip/hip_fp16.h>
#include <math.h>

typedef _Float16 f16x8 __attribute__((ext_vector_type(8)));
typedef _Float16 f16x2 __attribute__((ext_vector_type(2)));
typedef float f32x4 __attribute__((ext_vector_type(4)));

union U4H8 { uint4 u; f16x8 h; };
union U4D2 { uint4 u; f16x2 d2[4]; unsigned w[4]; };

// acc += f16_lo(pk) * s   /   acc += f16_hi(pk) * s   (single VALU op, f32 accumulate)
__device__ __forceinline__ float fmamix_lo(unsigned pk, float s, float acc) {
    asm("v_fma_mix_f32 %0, %1, %2, %0 op_sel:[0,0,0] op_sel_hi:[1,0,0]"
        : "+v"(acc) : "v"(pk), "v"(s));
    return acc;
}
__device__ __forceinline__ float fmamix_hi(unsigned pk, float s, float acc) {
    asm("v_fma_mix_f32 %0, %1, %2, %0 op_sel:[1,0,0] op_sel_hi:[1,0,0]"
        : "+v"(acc) : "v"(pk), "v"(s));
    return acc;
}
__device__ __forceinline__ float fdot2(f16x2 a, f16x2 b, float c) {
#if __has_builtin(__builtin_amdgcn_fdot2)
    return __builtin_amdgcn_fdot2(a, b, c, false);
#else
    asm("v_dot2_f32_f16 %0, %1, %2, %0" : "+v"(c) : "v"(a), "v"(b));
    return c;
#endif
}

__device__ __forceinline__ void unpack8(uint4 u, float* f) {
    union { uint4 u; __half2 h2[4]; } U; U.u = u;
    float2 a = __half22float2(U.h2[0]);
    float2 b = __half22float2(U.h2[1]);
    float2 c = __half22float2(U.h2[2]);
    float2 d = __half22float2(U.h2[3]);
    f[0] = a.x; f[1] = a.y; f[2] = b.x; f[3] = b.y;
    f[4] = c.x; f[5] = c.y; f[6] = d.x; f[7] = d.y;
}

// ---------- preprocessing ----------
__global__ void k_zero(int* p, int n) {
    int i = blockIdx.x * blockDim.x + threadIdx.x;
    if (i < n) p[i] = 0;
}

// 4-way multi-buffered count: edge i uses copy (i&3); rank within copy
__global__ void k_count(const int* __restrict__ dst, int* deg4, int* rank, int E, int N) {
    int i = blockIdx.x * blockDim.x + threadIdx.x;
    if (i < E) rank[i] = atomicAdd(&deg4[(i & 3) * N + dst[i]], 1);
}

// deg_tot + dis (fused)
__global__ void k_meta_pre(const int* __restrict__ deg4, int* deg, float* dis, int N) {
    int n = blockIdx.x * blockDim.x + threadIdx.x;
    if (n >= N) return;
    int d = deg4[n] + deg4[N + n] + deg4[2 * N + n] + deg4[3 * N + n];
    deg[n] = d;
    dis[n] = rsqrtf((float)(d + 1));  // +1 self loop
}

// meta[n] = { offs[n]+1, b1, b2, b3 } where b_c = prefix of copy counts
__global__ void k_meta_post(const int* __restrict__ deg4, const int* __restrict__ offs,
                            int4* meta, int N) {
    int n = blockIdx.x * blockDim.x + threadIdx.x;
    if (n >= N) return;
    int d0 = deg4[n], d1 = deg4[N + n], d2 = deg4[2 * N + n];
    meta[n] = make_int4(offs[n] + 1, d0, d0 + d1, d0 + d1 + d2);
}

__global__ void k_scan1(const int* __restrict__ deg, int* part, int N) {
    int base = blockIdx.x * 1024;
    int tid = threadIdx.x;
    int s = 0;
#pragma unroll
    for (int j = 0; j < 4; ++j) {
        int idx = base + tid * 4 + j;
        if (idx < N) s += deg[idx] + 1;
    }
    __shared__ int sm[256];
    sm[tid] = s;
    __syncthreads();
    for (int off = 128; off > 0; off >>= 1) {
        if (tid < off) sm[tid] += sm[tid + off];
        __syncthreads();
    }
    if (tid == 0) part[blockIdx.x] = sm[0];
}

__global__ void k_scan2(int* part, int nb, int* offs, int N) {
    if (blockIdx.x == 0 && threadIdx.x == 0) {
        int run = 0;
        for (int b = 0; b < nb; ++b) { int t = part[b]; part[b] = run; run += t; }
        offs[N] = run;
    }
}

__global__ void k_scan3(const int* __restrict__ deg, const int* __restrict__ part,
                        int* offs, int N) {
    __shared__ int sm[256];
    int base = blockIdx.x * 1024;
    int tid = threadIdx.x;
    int a[4];
    int s = 0;
#pragma unroll
    for (int j = 0; j < 4; ++j) {
        int idx = base + tid * 4 + j;
        a[j] = (idx < N) ? (deg[idx] + 1) : 0;
        s += a[j];
    }
    sm[tid] = s;
    __syncthreads();
    for (int off = 1; off < 256; off <<= 1) {
        int v = (tid >= off) ? sm[tid - off] : 0;
        __syncthreads();
        sm[tid] += v;
        __syncthreads();
    }
    int excl = sm[tid] - s + part[blockIdx.x];
#pragma unroll
    for (int j = 0; j < 4; ++j) {
        int idx = base + tid * 4 + j;
        if (idx < N) offs[idx] = excl;
        excl += a[j];
    }
}

// atomic-free fill: edge i -> csr[meta.x + base_c + rank]; tail adds self-loops at meta.x-1
__global__ void k_fill(const int* __restrict__ ei, int E, int N,
                       const int4* __restrict__ meta,
                       const int* __restrict__ rank, int* csr) {
    int i = blockIdx.x * blockDim.x + threadIdx.x;
    if (i < E) {
        int s = ei[i], d = ei[E + i];
        int c = i & 3;
        int4 m = meta[d];
        int base = (c == 0) ? 0 : ((c == 1) ? m.y : ((c == 2) ? m.z : m.w));
        csr[m.x + base + rank[i]] = s;
    } else if (i < E + N) {
        int n = i - E;
        csr[meta[n].x - 1] = n;
    }
}

__global__ void k_gstart(const int* __restrict__ batch, int N, int* gstart, int G) {
    int g = blockIdx.x * blockDim.x + threadIdx.x;
    if (g > G) return;
    int lo = 0, hi = N;
    while (lo < hi) {
        int mid = (lo + hi) >> 1;
        if (batch[mid] < g) lo = mid + 1; else hi = mid;
    }
    gstart[g] = lo;
}

// ---------- pre-scaled cast: g0 = fp16(dis * x) ----------
__global__ __launch_bounds__(256) void k_cast(
    const float* __restrict__ x, const float* __restrict__ dis,
    __half* __restrict__ hx, int npairs)
{
    int i = blockIdx.x * blockDim.x + threadIdx.x;
    if (i >= npairs) return;
    float2 v = ((const float2*)x)[i];
    float d = dis[i >> 6];
    ((__half2*)hx)[i] = __floats2half2_rn(d * v.x, d * v.y);
}

// ---------- W prep (all 5 layers, one launch): W = hi + lo fp16, frag order ----------
__global__ void k_prepw(const float* __restrict__ W0, const float* __restrict__ W1,
                        const float* __restrict__ W2, const float* __restrict__ W3,
                        const float* __restrict__ W4,
                        __half* __restrict__ wt_hi, __half* __restrict__ wt_lo) {
    int gid = blockIdx.x * 256 + threadIdx.x;   // 0..81919
    int layer = gid >> 14;
    int t = gid & 16383;
    const float* W = (layer == 0) ? W0 : (layer == 1) ? W1 : (layer == 2) ? W2
                     : (layer == 3) ? W3 : W4;
    int j = t & 7, q = t >> 3;
    int l15 = q & 15, nt = (q >> 4) & 7;
    int lg = (q >> 7) & 3, ks = q >> 9;
    int n = nt * 16 + l15, k = ks * 32 + lg * 8 + j;
    float w = W[k * 128 + n];
    __half hi = __float2half_rn(w);
    wt_hi[gid] = hi;
    wt_lo[gid] = __float2half_rn(w - __half2float(hi));
}

// ---------- GCN aggregation: 16 lanes/node, 8-deep gather pipeline, fma_mix ----------
__global__ __launch_bounds__(256) void k_gcn_agg(
    const __half* __restrict__ g, const int* __restrict__ csr,
    const int* __restrict__ offs, const float* __restrict__ dis,
    __half* __restrict__ agg, int N)
{
    int node = (blockIdx.x * blockDim.x + threadIdx.x) >> 4;
    int l = threadIdx.x & 15;
    if (node >= N) return;
    int j0 = offs[node], j1 = offs[node + 1];
    float dd = dis[node];
    const uint4* h4 = (const uint4*)g;
    float one = 1.0f;
    float acc[8] = {0.f, 0.f, 0.f, 0.f, 0.f, 0.f, 0.f, 0.f};
    int j = j0;
    for (; j + 8 <= j1; j += 8) {
        U4D2 u[8];
#pragma unroll
        for (int e = 0; e < 8; ++e) {
            int s = csr[j + e];
            u[e].u = h4[(unsigned)(s * 16 + l)];
        }
#pragma unroll
        for (int e = 0; e < 8; ++e)
#pragma unroll
            for (int k = 0; k < 4; ++k) {
                acc[2 * k]     = fmamix_lo(u[e].w[k], one, acc[2 * k]);
                acc[2 * k + 1] = fmamix_hi(u[e].w[k], one, acc[2 * k + 1]);
            }
    }
    for (; j + 4 <= j1; j += 4) {
        U4D2 u[4];
#pragma unroll
        for (int e = 0; e < 4; ++e) {
            int s = csr[j + e];
            u[e].u = h4[(unsigned)(s * 16 + l)];
        }
#pragma unroll
        for (int e = 0; e < 4; ++e)
#pragma unroll
            for (int k = 0; k < 4; ++k) {
                acc[2 * k]     = fmamix_lo(u[e].w[k], one, acc[2 * k]);
                acc[2 * k + 1] = fmamix_hi(u[e].w[k], one, acc[2 * k + 1]);
            }
    }
    for (; j < j1; ++j) {
        int s = csr[j];
        U4D2 u; u.u = h4[(unsigned)(s * 16 + l)];
#pragma unroll
        for (int k = 0; k < 4; ++k) {
            acc[2 * k]     = fmamix_lo(u.w[k], one, acc[2 * k]);
            acc[2 * k + 1] = fmamix_hi(u.w[k], one, acc[2 * k + 1]);
        }
    }
    union { uint4 u; __half2 h2[4]; } P;
    P.h2[0] = __floats2half2_rn(dd * acc[0], dd * acc[1]);
    P.h2[1] = __floats2half2_rn(dd * acc[2], dd * acc[3]);
    P.h2[2] = __floats2half2_rn(dd * acc[4], dd * acc[5]);
    P.h2[3] = __floats2half2_rn(dd * acc[6], dd * acc[7]);
    ((uint4*)agg)[(unsigned)(node * 16 + l)] = P.u;
}

// ---------- MFMA GEMM: out^T-tiles = W^T(hi+lo) · agg^T; LDS-staged full-line stores ----
#define GEMM_STG_OFF 65536
#define GEMM_STG_STRIDE 72
#define GEMM_LDS_BYTES (65536 + 8 * 16 * GEMM_STG_STRIDE)

__global__ __launch_bounds__(512) void k_gemm_mfma(
    const __half* __restrict__ in, const __half* __restrict__ wt_hi,
    const __half* __restrict__ wt_lo, const float* __restrict__ bias,
    const float* __restrict__ scale, __half* __restrict__ out,
    int ntiles, int nrows, float* __restrict__ invn_out)
{
    extern __shared__ char smem[];
    uint4* wlds = (uint4*)smem;
    int tid = threadIdx.x;
    int wv = tid >> 6;
    char* stg = smem + GEMM_STG_OFF + wv * 16 * GEMM_STG_STRIDE;

    {
        const uint4* sh = (const uint4*)wt_hi;
        const uint4* sl = (const uint4*)wt_lo;
        for (int t = tid; t < 2048; t += 512) {
            wlds[t] = sh[t];
            wlds[t + 2048] = sl[t];
        }
    }
    __syncthreads();

    int lane = tid & 63;
    int l15 = lane & 15, lg = lane >> 4;

    f32x4 bv[8];
#pragma unroll
    for (int nt = 0; nt < 8; ++nt)
        bv[nt] = *(const f32x4*)(bias + nt * 16 + lg * 4);

    int wid = blockIdx.x * 8 + wv;
    int t0 = wid * 2;
    for (int tile = t0; tile < t0 + 2 && tile < ntiles; ++tile) {
        int row0 = tile * 16;
        int row = row0 + l15;
        if (row >= nrows) row = nrows - 1;

        U4H8 b[4];
        const uint4* ap = (const uint4*)(in + (size_t)row * 128);
#pragma unroll
        for (int ks = 0; ks < 4; ++ks) b[ks].u = ap[ks * 4 + lg];

        f32x4 acc[8];
#pragma unroll
        for (int nt = 0; nt < 8; ++nt) acc[nt] = (f32x4){0.f, 0.f, 0.f, 0.f};

#pragma unroll
        for (int ks = 0; ks < 4; ++ks) {
#pragma unroll
            for (int nt = 0; nt < 8; ++nt) {
                int fi = (ks * 4 + lg) * 128 + nt * 16 + l15;
                U4H8 ah; ah.u = wlds[fi];
                U4H8 al; al.u = wlds[fi + 2048];
                acc[nt] = __builtin_amdgcn_mfma_f32_16x16x32_f16(ah.h, b[ks].h, acc[nt], 0, 0, 0);
                acc[nt] = __builtin_amdgcn_mfma_f32_16x16x32_f16(al.h, b[ks].h, acc[nt], 0, 0, 0);
            }
        }

        float sc = scale ? scale[row] : 1.0f;
        float sq = 0.f;
        int node = lane >> 2, sub = lane & 3;
#pragma unroll
        for (int np = 0; np < 4; ++np) {
#pragma unroll
            for (int h = 0; h < 2; ++h) {
                int nt = np * 2 + h;
                float o[4];
#pragma unroll
                for (int r = 0; r < 4; ++r) {
                    float xv = acc[nt][r] + bv[nt][r];
                    float e = __expf(xv + xv);        // tanh(x) = 1 - 2/(e^{2x}+1)
                    o[r] = 1.f - 2.f / (e + 1.f);
                    sq += o[r] * o[r];
                }
                union { __half2 h2[2]; uint2 u; } pk;
                pk.h2[0] = __floats2half2_rn(sc * o[0], sc * o[1]);
                pk.h2[1] = __floats2half2_rn(sc * o[2], sc * o[3]);
                *(uint2*)(stg + l15 * GEMM_STG_STRIDE + h * 32 + lg * 8) = pk.u;
            }
            uint4 v = *(const uint4*)(stg + node * GEMM_STG_STRIDE + sub * 16);
            if (row0 + node < nrows)
                *(uint4*)(out + (size_t)(row0 + node) * 128 + np * 32 + sub * 8) = v;
        }
        if (invn_out) {
            sq += __shfl_xor(sq, 16, 64);
            sq += __shfl_xor(sq, 32, 64);
            if (lg == 0) invn_out[row] = 1.0f / fmaxf(sqrtf(sq), 1e-12f);
        }
    }
}

// ---------- AGNN layer: 16 lanes/node, 6-deep gather pipeline, fdot2 + fma_mix ------
__global__ __launch_bounds__(256) void k_agnn(
    const __half* __restrict__ h, const int* __restrict__ csr,
    const int* __restrict__ offs, const float* __restrict__ invn,
    const float* __restrict__ beta_p, __half* __restrict__ out, int N,
    float* __restrict__ invn_out)
{
    int node = (blockIdx.x * blockDim.x + threadIdx.x) >> 4;
    int l = threadIdx.x & 15;
    if (node >= N) return;
    int j0 = offs[node], j1 = offs[node + 1];
    const uint4* h4 = (const uint4*)h;
    U4D2 D; D.u = h4[(unsigned)(node * 16 + l)];
    float bi = beta_p[0] * invn[node];
    float denom = 0.f;
    float acc[8] = {0.f, 0.f, 0.f, 0.f, 0.f, 0.f, 0.f, 0.f};
    int j = j0;
    for (; j + 6 <= j1; j += 6) {
        U4D2 A[6];
        float in_[6];
#pragma unroll
        for (int e = 0; e < 6; ++e) {
            int s = csr[j + e];
            in_[e] = invn[s];
            A[e].u = h4[(unsigned)(s * 16 + l)];
        }
        float d[6] = {0.f, 0.f, 0.f, 0.f, 0.f, 0.f};
#pragma unroll
        for (int e = 0; e < 6; ++e)
#pragma unroll
            for (int k = 0; k < 4; ++k) d[e] = fdot2(A[e].d2[k], D.d2[k], d[e]);
#pragma unroll
        for (int off = 1; off < 16; off <<= 1) {
#pragma unroll
            for (int e = 0; e < 6; ++e) d[e] += __shfl_xor(d[e], off, 64);
        }
        float p[6];
#pragma unroll
        for (int e = 0; e < 6; ++e) {
            p[e] = __expf(bi * in_[e] * d[e]);
            denom += p[e];
        }
#pragma unroll
        for (int e = 0; e < 6; ++e)
#pragma unroll
            for (int k = 0; k < 4; ++k) {
                acc[2 * k]     = fmamix_lo(A[e].w[k], p[e], acc[2 * k]);
                acc[2 * k + 1] = fmamix_hi(A[e].w[k], p[e], acc[2 * k + 1]);
            }
    }
    for (; j + 2 <= j1; j += 2) {
        U4D2 A[2];
        float in_[2];
#pragma unroll
        for (int e = 0; e < 2; ++e) {
            int s = csr[j + e];
            in_[e] = invn[s];
            A[e].u = h4[(unsigned)(s * 16 + l)];
        }
        float d[2] = {0.f, 0.f};
#pragma unroll
        for (int e = 0; e < 2; ++e)
#pragma unroll
            for (int k = 0; k < 4; ++k) d[e] = fdot2(A[e].d2[k], D.d2[k], d[e]);
#pragma unroll
        for (int off = 1; off < 16; off <<= 1) {
            d[0] += __shfl_xor(d[0], off, 64);
            d[1] += __shfl_xor(d[1], off, 64);
        }
        float p0 = __expf(bi * in_[0] * d[0]);
        float p1 = __expf(bi * in_[1] * d[1]);
        denom += p0 + p1;
#pragma unroll
        for (int k = 0; k < 4; ++k) {
            acc[2 * k]     = fmamix_lo(A[0].w[k], p0, acc[2 * k]);
            acc[2 * k + 1] = fmamix_hi(A[0].w[k], p0, acc[2 * k + 1]);
            acc[2 * k]     = fmamix_lo(A[1].w[k], p1, acc[2 * k]);
            acc[2 * k + 1] = fmamix_hi(A[1].w[k], p1, acc[2 * k + 1]);
        }
    }
    for (; j < j1; ++j) {
        int s = csr[j];
        float ins = invn[s];
        U4D2 A; A.u = h4[(unsigned)(s * 16 + l)];
        float d = 0.f;
#pragma unroll
        for (int k = 0; k < 4; ++k) d = fdot2(A.d2[k], D.d2[k], d);
#pragma unroll
        for (int off = 1; off < 16; off <<= 1) d += __shfl_xor(d, off, 64);
        float p = __expf(bi * ins * d);
        denom += p;
#pragma unroll
        for (int k = 0; k < 4; ++k) {
            acc[2 * k]     = fmamix_lo(A.w[k], p, acc[2 * k]);
            acc[2 * k + 1] = fmamix_hi(A.w[k], p, acc[2 * k + 1]);
        }
    }
    float inv = 1.0f / denom;
    float o[8];
#pragma unroll
    for (int i = 0; i < 8; ++i) o[i] = tanhf(acc[i] * inv);
    union { uint4 u; __half2 h2[4]; } P;
    P.h2[0] = __floats2half2_rn(o[0], o[1]);
    P.h2[1] = __floats2half2_rn(o[2], o[3]);
    P.h2[2] = __floats2half2_rn(o[4], o[5]);
    P.h2[3] = __floats2half2_rn(o[6], o[7]);
    ((uint4*)out)[(unsigned)(node * 16 + l)] = P.u;
    if (invn_out) {
        float s2 = 0.f;
#pragma unroll
        for (int i = 0; i < 8; ++i) s2 += o[i] * o[i];
#pragma unroll
        for (int off = 1; off < 16; off <<= 1) s2 += __shfl_xor(s2, off, 64);
        if (l == 0) invn_out[node] = 1.0f / fmaxf(sqrtf(s2), 1e-12f);
    }
}

// ---------- per-graph mean pool + layernorm + final linear (16 lanes/graph) ----------
__global__ __launch_bounds__(256) void k_pool(
    const __half* __restrict__ h, const int* __restrict__ gstart,
    const float* __restrict__ Wl, const float* __restrict__ bl,
    float* __restrict__ out, int G)
{
    int g = (blockIdx.x * blockDim.x + threadIdx.x) >> 4;
    int l = threadIdx.x & 15;
    if (g >= G) return;
    int s = gstart[g], e = gstart[g + 1];
    const uint4* hp = (const uint4*)h + l;
    float acc[8] = {0.f, 0.f, 0.f, 0.f, 0.f, 0.f, 0.f, 0.f};
    for (int n = s; n < e; ++n) {
        float f[8]; unpack8(hp[(size_t)n * 16], f);
#pragma unroll
        for (int i = 0; i < 8; ++i) acc[i] += f[i];
    }
    float inv = 1.0f / fmaxf((float)(e - s), 1.0f);
#pragma unroll
    for (int i = 0; i < 8; ++i) acc[i] *= inv;
    float part = 0.f;
#pragma unroll
    for (int i = 0; i < 8; ++i) part += acc[i];
#pragma unroll
    for (int off = 1; off < 16; off <<= 1) part += __shfl_xor(part, off, 64);
    float mu = part * (1.0f / 128.0f);
    float vpart = 0.f;
#pragma unroll
    for (int i = 0; i < 8; ++i) { float d = acc[i] - mu; vpart += d * d; }
#pragma unroll
    for (int off = 1; off < 16; off <<= 1) vpart += __shfl_xor(vpart, off, 64);
    float r = rsqrtf(vpart * (1.0f / 128.0f) + 1e-5f);
    float4 w0 = *(const float4*)(Wl + l * 8);
    float4 w1 = *(const float4*)(Wl + l * 8 + 4);
    float wv[8] = {w0.x, w0.y, w0.z, w0.w, w1.x, w1.y, w1.z, w1.w};
    float dot = 0.f;
#pragma unroll
    for (int i = 0; i < 8; ++i) dot += (acc[i] - mu) * r * wv[i];
#pragma unroll
    for (int off = 1; off < 16; off <<= 1) dot += __shfl_xor(dot, off, 64);
    if (l == 0) out[g] = dot + bl[0];
}

extern "C" void kernel_launch(void* const* d_in, const int* in_sizes, int n_in,
                              void* d_out, int out_size, void* d_ws, size_t ws_size,
                              hipStream_t stream) {
    const float* x  = (const float*)d_in[0];
    const int* ei   = (const int*)d_in[1];      // [2][E]
    const int* batch = (const int*)d_in[2];
    const float* Ws[5] = {(const float*)d_in[3], (const float*)d_in[5],
                          (const float*)d_in[7], (const float*)d_in[9],
                          (const float*)d_in[11]};
    const float* bs[5] = {(const float*)d_in[4], (const float*)d_in[6],
                          (const float*)d_in[8], (const float*)d_in[10],
                          (const float*)d_in[12]};
    const float* beta1 = (const float*)d_in[13];
    const float* beta2 = (const float*)d_in[14];
    const float* Wl = (const float*)d_in[15];
    const float* bl = (const float*)d_in[16];
    float* out = (float*)d_out;

    int N = in_sizes[0] / 128;
    int E = in_sizes[1] / 2;
    int G = out_size;

    char* ws = (char*)d_ws;
    size_t off = 0;
    auto alloc = [&](size_t bytes) -> void* {
        void* p = ws + off;
        off = (off + bytes + 255) & ~(size_t)255;
        return p;
    };
    __half* aggh = (__half*)alloc((size_t)N * 128 * 2);
    __half* hA   = (__half*)alloc((size_t)N * 128 * 2);
    __half* hB   = (__half*)alloc((size_t)N * 128 * 2);
    int*   deg4  = (int*)alloc((size_t)4 * N * 4);
    int*   deg   = (int*)alloc((size_t)N * 4);
    int*   offs  = (int*)alloc((size_t)(N + 1) * 4);
    int4*  meta  = (int4*)alloc((size_t)N * 16);
    int*   rank  = (int*)alloc((size_t)E * 4);
    int*   csr   = (int*)alloc((size_t)(E + N) * 4);
    float* dis   = (float*)alloc((size_t)N * 4);
    float* invn  = (float*)alloc((size_t)N * 4);
    float* invn2 = (float*)alloc((size_t)N * 4);
    __half* wtHi = (__half*)alloc((size_t)5 * 16384 * 2);
    __half* wtLo = (__half*)alloc((size_t)5 * 16384 * 2);
    int nb = (N + 1023) / 1024;
    int*   part  = (int*)alloc((size_t)nb * 4);
    int*   gst   = (int*)alloc((size_t)(G + 1) * 4);

    // CSR build (4-way multi-buffered count, atomic-free fill) + x cast + W prep
    k_zero<<<(4 * N + 255) / 256, 256, 0, stream>>>(deg4, 4 * N);
    k_count<<<(E + 255) / 256, 256, 0, stream>>>(ei + E, deg4, rank, E, N);
    k_meta_pre<<<(N + 255) / 256, 256, 0, stream>>>(deg4, deg, dis, N);
    k_scan1<<<nb, 256, 0, stream>>>(deg, part, N);
    k_scan2<<<1, 64, 0, stream>>>(part, nb, offs, N);
    k_scan3<<<nb, 256, 0, stream>>>(deg, part, offs, N);
    k_meta_post<<<(N + 255) / 256, 256, 0, stream>>>(deg4, offs, meta, N);
    k_fill<<<(E + N + 255) / 256, 256, 0, stream>>>(ei, E, N, meta, rank, csr);
    k_gstart<<<(G + 1 + 255) / 256, 256, 0, stream>>>(batch, N, gst, G);
    k_cast<<<(N * 64 + 255) / 256, 256, 0, stream>>>(x, dis, hA, N * 64);
    k_prepw<<<320, 256, 0, stream>>>(Ws[0], Ws[1], Ws[2], Ws[3], Ws[4], wtHi, wtLo);

    int aggBlocks = (N + 15) / 16;   // 16 nodes per 256-thread block
    int ntiles = (N + 15) / 16;
    int gemmBlocks = (ntiles + 15) / 16;   // 8 waves/block, 2 tiles/wave

    // 5 GCN layers; layers 0-3 write dis-scaled fp16; layer 4 writes unscaled + invn
    const __half* hin = hA;
    __half* hout = hB;
    for (int l = 0; l < 5; ++l) {
        k_gcn_agg<<<aggBlocks, 256, 0, stream>>>(hin, csr, offs, dis, aggh, N);
        k_gemm_mfma<<<gemmBlocks, 512, GEMM_LDS_BYTES, stream>>>(
            aggh, wtHi + l * 16384, wtLo + l * 16384, bs[l],
            (l < 4) ? dis : nullptr, hout, ntiles, N,
            (l == 4) ? invn : nullptr);
        const __half* t = hin; hin = hout; hout = (__half*)t;
    }
    // after loop: hin = h5 (hB), hout = hA
    k_agnn<<<aggBlocks, 256, 0, stream>>>(hin, csr, offs, invn, beta1, hout, N, invn2);
    k_agnn<<<aggBlocks, 256, 0, stream>>>(hout, csr, offs, invn2, beta2, (__half*)hin, N, nullptr);
    k_pool<<<(G + 15) / 16, 256, 0, stream>>>(hin, gst, Wl, bl, out, G);
}

// Round 16
// 712.492 us; speedup vs baseline: 1.0342x; 1.0199x over previous
//
#include <hip/hip_runtime.h>
#include <hip/hip_fp16.h>
#include <math.h>

typedef _Float16 f16x8 __attribute__((ext_vector_type(8)));
typedef _Float16 f16x2 __attribute__((ext_vector_type(2)));
typedef float f32x4 __attribute__((ext_vector_type(4)));

union U4H8 { uint4 u; f16x8 h; };
union U4D2 { uint4 u; f16x2 d2[4]; unsigned w[4]; };

// acc += f16_lo(pk) * s   /   acc += f16_hi(pk) * s   (single VALU op, f32 accumulate)
__device__ __forceinline__ float fmamix_lo(unsigned pk, float s, float acc) {
    asm("v_fma_mix_f32 %0, %1, %2, %0 op_sel:[0,0,0] op_sel_hi:[1,0,0]"
        : "+v"(acc) : "v"(pk), "v"(s));
    return acc;
}
__device__ __forceinline__ float fmamix_hi(unsigned pk, float s, float acc) {
    asm("v_fma_mix_f32 %0, %1, %2, %0 op_sel:[1,0,0] op_sel_hi:[1,0,0]"
        : "+v"(acc) : "v"(pk), "v"(s));
    return acc;
}
__device__ __forceinline__ float fdot2(f16x2 a, f16x2 b, float c) {
#if __has_builtin(__builtin_amdgcn_fdot2)
    return __builtin_amdgcn_fdot2(a, b, c, false);
#else
    asm("v_dot2_f32_f16 %0, %1, %2, %0" : "+v"(c) : "v"(a), "v"(b));
    return c;
#endif
}

__device__ __forceinline__ void unpack8(uint4 u, float* f) {
    union { uint4 u; __half2 h2[4]; } U; U.u = u;
    float2 a = __half22float2(U.h2[0]);
    float2 b = __half22float2(U.h2[1]);
    float2 c = __half22float2(U.h2[2]);
    float2 d = __half22float2(U.h2[3]);
    f[0] = a.x; f[1] = a.y; f[2] = b.x; f[3] = b.y;
    f[4] = c.x; f[5] = c.y; f[6] = d.x; f[7] = d.y;
}

// ---------- preprocessing ----------
__global__ void k_zero(int* p, int n) {
    int i = blockIdx.x * blockDim.x + threadIdx.x;
    if (i < n) p[i] = 0;
}

// 4-way multi-buffered count: edge i uses copy (i&3); rank within copy
__global__ void k_count(const int* __restrict__ dst, int* deg4, int* rank, int E, int N) {
    int i = blockIdx.x * blockDim.x + threadIdx.x;
    if (i < E) rank[i] = atomicAdd(&deg4[(i & 3) * N + dst[i]], 1);
}

// deg_tot + dis (fused)
__global__ void k_meta_pre(const int* __restrict__ deg4, int* deg, float* dis, int N) {
    int n = blockIdx.x * blockDim.x + threadIdx.x;
    if (n >= N) return;
    int d = deg4[n] + deg4[N + n] + deg4[2 * N + n] + deg4[3 * N + n];
    deg[n] = d;
    dis[n] = rsqrtf((float)(d + 1));  // +1 self loop
}

// meta[n] = { offs[n]+1, b1, b2, b3 } where b_c = prefix of copy counts
__global__ void k_meta_post(const int* __restrict__ deg4, const int* __restrict__ offs,
                            int4* meta, int N) {
    int n = blockIdx.x * blockDim.x + threadIdx.x;
    if (n >= N) return;
    int d0 = deg4[n], d1 = deg4[N + n], d2 = deg4[2 * N + n];
    meta[n] = make_int4(offs[n] + 1, d0, d0 + d1, d0 + d1 + d2);
}

__global__ void k_scan1(const int* __restrict__ deg, int* part, int N) {
    int base = blockIdx.x * 1024;
    int tid = threadIdx.x;
    int s = 0;
#pragma unroll
    for (int j = 0; j < 4; ++j) {
        int idx = base + tid * 4 + j;
        if (idx < N) s += deg[idx] + 1;
    }
    __shared__ int sm[256];
    sm[tid] = s;
    __syncthreads();
    for (int off = 128; off > 0; off >>= 1) {
        if (tid < off) sm[tid] += sm[tid + off];
        __syncthreads();
    }
    if (tid == 0) part[blockIdx.x] = sm[0];
}

__global__ void k_scan2(int* part, int nb, int* offs, int N) {
    if (blockIdx.x == 0 && threadIdx.x == 0) {
        int run = 0;
        for (int b = 0; b < nb; ++b) { int t = part[b]; part[b] = run; run += t; }
        offs[N] = run;
    }
}

__global__ void k_scan3(const int* __restrict__ deg, const int* __restrict__ part,
                        int* offs, int N) {
    __shared__ int sm[256];
    int base = blockIdx.x * 1024;
    int tid = threadIdx.x;
    int a[4];
    int s = 0;
#pragma unroll
    for (int j = 0; j < 4; ++j) {
        int idx = base + tid * 4 + j;
        a[j] = (idx < N) ? (deg[idx] + 1) : 0;
        s += a[j];
    }
    sm[tid] = s;
    __syncthreads();
    for (int off = 1; off < 256; off <<= 1) {
        int v = (tid >= off) ? sm[tid - off] : 0;
        __syncthreads();
        sm[tid] += v;
        __syncthreads();
    }
    int excl = sm[tid] - s + part[blockIdx.x];
#pragma unroll
    for (int j = 0; j < 4; ++j) {
        int idx = base + tid * 4 + j;
        if (idx < N) offs[idx] = excl;
        excl += a[j];
    }
}

// atomic-free fill: edge i -> csr[meta.x + base_c + rank]; tail adds self-loops at meta.x-1
__global__ void k_fill(const int* __restrict__ ei, int E, int N,
                       const int4* __restrict__ meta,
                       const int* __restrict__ rank, int* csr) {
    int i = blockIdx.x * blockDim.x + threadIdx.x;
    if (i < E) {
        int s = ei[i], d = ei[E + i];
        int c = i & 3;
        int4 m = meta[d];
        int base = (c == 0) ? 0 : ((c == 1) ? m.y : ((c == 2) ? m.z : m.w));
        csr[m.x + base + rank[i]] = s;
    } else if (i < E + N) {
        int n = i - E;
        csr[meta[n].x - 1] = n;
    }
}

__global__ void k_gstart(const int* __restrict__ batch, int N, int* gstart, int G) {
    int g = blockIdx.x * blockDim.x + threadIdx.x;
    if (g > G) return;
    int lo = 0, hi = N;
    while (lo < hi) {
        int mid = (lo + hi) >> 1;
        if (batch[mid] < g) lo = mid + 1; else hi = mid;
    }
    gstart[g] = lo;
}

// ---------- pre-scaled cast: g0 = fp16(dis * x) ----------
__global__ __launch_bounds__(256) void k_cast(
    const float* __restrict__ x, const float* __restrict__ dis,
    __half* __restrict__ hx, int npairs)
{
    int i = blockIdx.x * blockDim.x + threadIdx.x;
    if (i >= npairs) return;
    float2 v = ((const float2*)x)[i];
    float d = dis[i >> 6];
    ((__half2*)hx)[i] = __floats2half2_rn(d * v.x, d * v.y);
}

// ---------- W prep (all 5 layers, one launch): W = hi + lo fp16, frag order ----------
__global__ void k_prepw(const float* __restrict__ W0, const float* __restrict__ W1,
                        const float* __restrict__ W2, const float* __restrict__ W3,
                        const float* __restrict__ W4,
                        __half* __restrict__ wt_hi, __half* __restrict__ wt_lo) {
    int gid = blockIdx.x * 256 + threadIdx.x;   // 0..81919
    int layer = gid >> 14;
    int t = gid & 16383;
    const float* W = (layer == 0) ? W0 : (layer == 1) ? W1 : (layer == 2) ? W2
                     : (layer == 3) ? W3 : W4;
    int j = t & 7, q = t >> 3;
    int l15 = q & 15, nt = (q >> 4) & 7;
    int lg = (q >> 7) & 3, ks = q >> 9;
    int n = nt * 16 + l15, k = ks * 32 + lg * 8 + j;
    float w = W[k * 128 + n];
    __half hi = __float2half_rn(w);
    wt_hi[gid] = hi;
    wt_lo[gid] = __float2half_rn(w - __half2float(hi));
}

// ---------- GCN aggregation: 16 lanes/node, 8-deep gather pipeline, fma_mix ----------
__global__ __launch_bounds__(256) void k_gcn_agg(
    const __half* __restrict__ g, const int* __restrict__ csr,
    const int* __restrict__ offs, const float* __restrict__ dis,
    __half* __restrict__ agg, int N)
{
    int node = (blockIdx.x * blockDim.x + threadIdx.x) >> 4;
    int l = threadIdx.x & 15;
    if (node >= N) return;
    int j0 = offs[node], j1 = offs[node + 1];
    float dd = dis[node];
    const uint4* h4 = (const uint4*)g;
    float one = 1.0f;
    float acc[8] = {0.f, 0.f, 0.f, 0.f, 0.f, 0.f, 0.f, 0.f};
    int j = j0;
    for (; j + 8 <= j1; j += 8) {
        U4D2 u[8];
#pragma unroll
        for (int e = 0; e < 8; ++e) {
            int s = csr[j + e];
            u[e].u = h4[(unsigned)(s * 16 + l)];
        }
#pragma unroll
        for (int e = 0; e < 8; ++e)
#pragma unroll
            for (int k = 0; k < 4; ++k) {
                acc[2 * k]     = fmamix_lo(u[e].w[k], one, acc[2 * k]);
                acc[2 * k + 1] = fmamix_hi(u[e].w[k], one, acc[2 * k + 1]);
            }
    }
    for (; j + 4 <= j1; j += 4) {
        U4D2 u[4];
#pragma unroll
        for (int e = 0; e < 4; ++e) {
            int s = csr[j + e];
            u[e].u = h4[(unsigned)(s * 16 + l)];
        }
#pragma unroll
        for (int e = 0; e < 4; ++e)
#pragma unroll
            for (int k = 0; k < 4; ++k) {
                acc[2 * k]     = fmamix_lo(u[e].w[k], one, acc[2 * k]);
                acc[2 * k + 1] = fmamix_hi(u[e].w[k], one, acc[2 * k + 1]);
            }
    }
    for (; j < j1; ++j) {
        int s = csr[j];
        U4D2 u; u.u = h4[(unsigned)(s * 16 + l)];
#pragma unroll
        for (int k = 0; k < 4; ++k) {
            acc[2 * k]     = fmamix_lo(u.w[k], one, acc[2 * k]);
            acc[2 * k + 1] = fmamix_hi(u.w[k], one, acc[2 * k + 1]);
        }
    }
    union { uint4 u; __half2 h2[4]; } P;
    P.h2[0] = __floats2half2_rn(dd * acc[0], dd * acc[1]);
    P.h2[1] = __floats2half2_rn(dd * acc[2], dd * acc[3]);
    P.h2[2] = __floats2half2_rn(dd * acc[4], dd * acc[5]);
    P.h2[3] = __floats2half2_rn(dd * acc[6], dd * acc[7]);
    ((uint4*)agg)[(unsigned)(node * 16 + l)] = P.u;
}

// ---------- MFMA GEMM: out^T-tiles = W^T(hi+lo) · agg^T; LDS-staged full-line stores ----
#define GEMM_STG_OFF 65536
#define GEMM_STG_STRIDE 72
#define GEMM_LDS_BYTES (65536 + 8 * 16 * GEMM_STG_STRIDE)

__global__ __launch_bounds__(512) void k_gemm_mfma(
    const __half* __restrict__ in, const __half* __restrict__ wt_hi,
    const __half* __restrict__ wt_lo, const float* __restrict__ bias,
    const float* __restrict__ scale, __half* __restrict__ out,
    int ntiles, int nrows, float* __restrict__ invn_out)
{
    extern __shared__ char smem[];
    uint4* wlds = (uint4*)smem;
    int tid = threadIdx.x;
    int wv = tid >> 6;
    char* stg = smem + GEMM_STG_OFF + wv * 16 * GEMM_STG_STRIDE;

    {
        const uint4* sh = (const uint4*)wt_hi;
        const uint4* sl = (const uint4*)wt_lo;
        for (int t = tid; t < 2048; t += 512) {
            wlds[t] = sh[t];
            wlds[t + 2048] = sl[t];
        }
    }
    __syncthreads();

    int lane = tid & 63;
    int l15 = lane & 15, lg = lane >> 4;

    f32x4 bv[8];
#pragma unroll
    for (int nt = 0; nt < 8; ++nt)
        bv[nt] = *(const f32x4*)(bias + nt * 16 + lg * 4);

    int wid = blockIdx.x * 8 + wv;
    int t0 = wid * 4;
    for (int tile = t0; tile < t0 + 4 && tile < ntiles; ++tile) {
        int row0 = tile * 16;
        int row = row0 + l15;
        if (row >= nrows) row = nrows - 1;

        U4H8 b[4];
        const uint4* ap = (const uint4*)(in + (size_t)row * 128);
#pragma unroll
        for (int ks = 0; ks < 4; ++ks) b[ks].u = ap[ks * 4 + lg];

        f32x4 acc[8];
#pragma unroll
        for (int nt = 0; nt < 8; ++nt) acc[nt] = (f32x4){0.f, 0.f, 0.f, 0.f};

#pragma unroll
        for (int ks = 0; ks < 4; ++ks) {
#pragma unroll
            for (int nt = 0; nt < 8; ++nt) {
                int fi = (ks * 4 + lg) * 128 + nt * 16 + l15;
                U4H8 ah; ah.u = wlds[fi];
                U4H8 al; al.u = wlds[fi + 2048];
                acc[nt] = __builtin_amdgcn_mfma_f32_16x16x32_f16(ah.h, b[ks].h, acc[nt], 0, 0, 0);
                acc[nt] = __builtin_amdgcn_mfma_f32_16x16x32_f16(al.h, b[ks].h, acc[nt], 0, 0, 0);
            }
        }

        float sc = scale ? scale[row] : 1.0f;
        float sq = 0.f;
        int node = lane >> 2, sub = lane & 3;
#pragma unroll
        for (int np = 0; np < 4; ++np) {
#pragma unroll
            for (int h = 0; h < 2; ++h) {
                int nt = np * 2 + h;
                float o[4];
#pragma unroll
                for (int r = 0; r < 4; ++r) {
                    float xv = acc[nt][r] + bv[nt][r];
                    float e = __expf(xv + xv);        // tanh(x) = 1 - 2/(e^{2x}+1)
                    o[r] = 1.f - 2.f / (e + 1.f);
                    sq += o[r] * o[r];
                }
                union { __half2 h2[2]; uint2 u; } pk;
                pk.h2[0] = __floats2half2_rn(sc * o[0], sc * o[1]);
                pk.h2[1] = __floats2half2_rn(sc * o[2], sc * o[3]);
                *(uint2*)(stg + l15 * GEMM_STG_STRIDE + h * 32 + lg * 8) = pk.u;
            }
            uint4 v = *(const uint4*)(stg + node * GEMM_STG_STRIDE + sub * 16);
            if (row0 + node < nrows)
                *(uint4*)(out + (size_t)(row0 + node) * 128 + np * 32 + sub * 8) = v;
        }
        if (invn_out) {
            sq += __shfl_xor(sq, 16, 64);
            sq += __shfl_xor(sq, 32, 64);
            if (lg == 0) invn_out[row] = 1.0f / fmaxf(sqrtf(sq), 1e-12f);
        }
    }
}

// ---------- AGNN layer: 16 lanes/node, 4-deep gather pipeline, fdot2 + fma_mix ------
__global__ __launch_bounds__(256) void k_agnn(
    const __half* __restrict__ h, const int* __restrict__ csr,
    const int* __restrict__ offs, const float* __restrict__ invn,
    const float* __restrict__ beta_p, __half* __restrict__ out, int N,
    float* __restrict__ invn_out)
{
    int node = (blockIdx.x * blockDim.x + threadIdx.x) >> 4;
    int l = threadIdx.x & 15;
    if (node >= N) return;
    int j0 = offs[node], j1 = offs[node + 1];
    const uint4* h4 = (const uint4*)h;
    U4D2 D; D.u = h4[(unsigned)(node * 16 + l)];
    float bi = beta_p[0] * invn[node];
    float denom = 0.f;
    float acc[8] = {0.f, 0.f, 0.f, 0.f, 0.f, 0.f, 0.f, 0.f};
    int j = j0;
    for (; j + 4 <= j1; j += 4) {
        U4D2 A[4];
        float in_[4];
#pragma unroll
        for (int e = 0; e < 4; ++e) {
            int s = csr[j + e];
            in_[e] = invn[s];
            A[e].u = h4[(unsigned)(s * 16 + l)];
        }
        float d[4] = {0.f, 0.f, 0.f, 0.f};
#pragma unroll
        for (int e = 0; e < 4; ++e)
#pragma unroll
            for (int k = 0; k < 4; ++k) d[e] = fdot2(A[e].d2[k], D.d2[k], d[e]);
#pragma unroll
        for (int off = 1; off < 16; off <<= 1) {
            d[0] += __shfl_xor(d[0], off, 64);
            d[1] += __shfl_xor(d[1], off, 64);
            d[2] += __shfl_xor(d[2], off, 64);
            d[3] += __shfl_xor(d[3], off, 64);
        }
        float p[4];
#pragma unroll
        for (int e = 0; e < 4; ++e) {
            p[e] = __expf(bi * in_[e] * d[e]);
            denom += p[e];
        }
#pragma unroll
        for (int e = 0; e < 4; ++e)
#pragma unroll
            for (int k = 0; k < 4; ++k) {
                acc[2 * k]     = fmamix_lo(A[e].w[k], p[e], acc[2 * k]);
                acc[2 * k + 1] = fmamix_hi(A[e].w[k], p[e], acc[2 * k + 1]);
            }
    }
    for (; j < j1; ++j) {
        int s = csr[j];
        float ins = invn[s];
        U4D2 A; A.u = h4[(unsigned)(s * 16 + l)];
        float d = 0.f;
#pragma unroll
        for (int k = 0; k < 4; ++k) d = fdot2(A.d2[k], D.d2[k], d);
#pragma unroll
        for (int off = 1; off < 16; off <<= 1) d += __shfl_xor(d, off, 64);
        float p = __expf(bi * ins * d);
        denom += p;
#pragma unroll
        for (int k = 0; k < 4; ++k) {
            acc[2 * k]     = fmamix_lo(A.w[k], p, acc[2 * k]);
            acc[2 * k + 1] = fmamix_hi(A.w[k], p, acc[2 * k + 1]);
        }
    }
    float inv = 1.0f / denom;
    float o[8];
#pragma unroll
    for (int i = 0; i < 8; ++i) o[i] = tanhf(acc[i] * inv);
    union { uint4 u; __half2 h2[4]; } P;
    P.h2[0] = __floats2half2_rn(o[0], o[1]);
    P.h2[1] = __floats2half2_rn(o[2], o[3]);
    P.h2[2] = __floats2half2_rn(o[4], o[5]);
    P.h2[3] = __floats2half2_rn(o[6], o[7]);
    ((uint4*)out)[(unsigned)(node * 16 + l)] = P.u;
    if (invn_out) {
        float s2 = 0.f;
#pragma unroll
        for (int i = 0; i < 8; ++i) s2 += o[i] * o[i];
#pragma unroll
        for (int off = 1; off < 16; off <<= 1) s2 += __shfl_xor(s2, off, 64);
        if (l == 0) invn_out[node] = 1.0f / fmaxf(sqrtf(s2), 1e-12f);
    }
}

// ---------- per-graph mean pool + layernorm + final linear (16 lanes/graph) ----------
__global__ __launch_bounds__(256) void k_pool(
    const __half* __restrict__ h, const int* __restrict__ gstart,
    const float* __restrict__ Wl, const float* __restrict__ bl,
    float* __restrict__ out, int G)
{
    int g = (blockIdx.x * blockDim.x + threadIdx.x) >> 4;
    int l = threadIdx.x & 15;
    if (g >= G) return;
    int s = gstart[g], e = gstart[g + 1];
    const uint4* hp = (const uint4*)h + l;
    float acc[8] = {0.f, 0.f, 0.f, 0.f, 0.f, 0.f, 0.f, 0.f};
    for (int n = s; n < e; ++n) {
        float f[8]; unpack8(hp[(size_t)n * 16], f);
#pragma unroll
        for (int i = 0; i < 8; ++i) acc[i] += f[i];
    }
    float inv = 1.0f / fmaxf((float)(e - s), 1.0f);
#pragma unroll
    for (int i = 0; i < 8; ++i) acc[i] *= inv;
    float part = 0.f;
#pragma unroll
    for (int i = 0; i < 8; ++i) part += acc[i];
#pragma unroll
    for (int off = 1; off < 16; off <<= 1) part += __shfl_xor(part, off, 64);
    float mu = part * (1.0f / 128.0f);
    float vpart = 0.f;
#pragma unroll
    for (int i = 0; i < 8; ++i) { float d = acc[i] - mu; vpart += d * d; }
#pragma unroll
    for (int off = 1; off < 16; off <<= 1) vpart += __shfl_xor(vpart, off, 64);
    float r = rsqrtf(vpart * (1.0f / 128.0f) + 1e-5f);
    float4 w0 = *(const float4*)(Wl + l * 8);
    float4 w1 = *(const float4*)(Wl + l * 8 + 4);
    float wv[8] = {w0.x, w0.y, w0.z, w0.w, w1.x, w1.y, w1.z, w1.w};
    float dot = 0.f;
#pragma unroll
    for (int i = 0; i < 8; ++i) dot += (acc[i] - mu) * r * wv[i];
#pragma unroll
    for (int off = 1; off < 16; off <<= 1) dot += __shfl_xor(dot, off, 64);
    if (l == 0) out[g] = dot + bl[0];
}

extern "C" void kernel_launch(void* const* d_in, const int* in_sizes, int n_in,
                              void* d_out, int out_size, void* d_ws, size_t ws_size,
                              hipStream_t stream) {
    const float* x  = (const float*)d_in[0];
    const int* ei   = (const int*)d_in[1];      // [2][E]
    const int* batch = (const int*)d_in[2];
    const float* Ws[5] = {(const float*)d_in[3], (const float*)d_in[5],
                          (const float*)d_in[7], (const float*)d_in[9],
                          (const float*)d_in[11]};
    const float* bs[5] = {(const float*)d_in[4], (const float*)d_in[6],
                          (const float*)d_in[8], (const float*)d_in[10],
                          (const float*)d_in[12]};
    const float* beta1 = (const float*)d_in[13];
    const float* beta2 = (const float*)d_in[14];
    const float* Wl = (const float*)d_in[15];
    const float* bl = (const float*)d_in[16];
    float* out = (float*)d_out;

    int N = in_sizes[0] / 128;
    int E = in_sizes[1] / 2;
    int G = out_size;

    char* ws = (char*)d_ws;
    size_t off = 0;
    auto alloc = [&](size_t bytes) -> void* {
        void* p = ws + off;
        off = (off + bytes + 255) & ~(size_t)255;
        return p;
    };
    __half* aggh = (__half*)alloc((size_t)N * 128 * 2);
    __half* hA   = (__half*)alloc((size_t)N * 128 * 2);
    __half* hB   = (__half*)alloc((size_t)N * 128 * 2);
    int*   deg4  = (int*)alloc((size_t)4 * N * 4);
    int*   deg   = (int*)alloc((size_t)N * 4);
    int*   offs  = (int*)alloc((size_t)(N + 1) * 4);
    int4*  meta  = (int4*)alloc((size_t)N * 16);
    int*   rank  = (int*)alloc((size_t)E * 4);
    int*   csr   = (int*)alloc((size_t)(E + N) * 4);
    float* dis   = (float*)alloc((size_t)N * 4);
    float* invn  = (float*)alloc((size_t)N * 4);
    float* invn2 = (float*)alloc((size_t)N * 4);
    __half* wtHi = (__half*)alloc((size_t)5 * 16384 * 2);
    __half* wtLo = (__half*)alloc((size_t)5 * 16384 * 2);
    int nb = (N + 1023) / 1024;
    int*   part  = (int*)alloc((size_t)nb * 4);
    int*   gst   = (int*)alloc((size_t)(G + 1) * 4);

    // CSR build (4-way multi-buffered count, atomic-free fill) + x cast + W prep
    k_zero<<<(4 * N + 255) / 256, 256, 0, stream>>>(deg4, 4 * N);
    k_count<<<(E + 255) / 256, 256, 0, stream>>>(ei + E, deg4, rank, E, N);
    k_meta_pre<<<(N + 255) / 256, 256, 0, stream>>>(deg4, deg, dis, N);
    k_scan1<<<nb, 256, 0, stream>>>(deg, part, N);
    k_scan2<<<1, 64, 0, stream>>>(part, nb, offs, N);
    k_scan3<<<nb, 256, 0, stream>>>(deg, part, offs, N);
    k_meta_post<<<(N + 255) / 256, 256, 0, stream>>>(deg4, offs, meta, N);
    k_fill<<<(E + N + 255) / 256, 256, 0, stream>>>(ei, E, N, meta, rank, csr);
    k_gstart<<<(G + 1 + 255) / 256, 256, 0, stream>>>(batch, N, gst, G);
    k_cast<<<(N * 64 + 255) / 256, 256, 0, stream>>>(x, dis, hA, N * 64);
    k_prepw<<<320, 256, 0, stream>>>(Ws[0], Ws[1], Ws[2], Ws[3], Ws[4], wtHi, wtLo);

    int aggBlocks = (N + 15) / 16;   // 16 nodes per 256-thread block
    int ntiles = (N + 15) / 16;
    int gemmBlocks = (ntiles + 31) / 32;   // 8 waves/block, 4 tiles/wave

    // 5 GCN layers; layers 0-3 write dis-scaled fp16; layer 4 writes unscaled + invn
    const __half* hin = hA;
    __half* hout = hB;
    for (int l = 0; l < 5; ++l) {
        k_gcn_agg<<<aggBlocks, 256, 0, stream>>>(hin, csr, offs, dis, aggh, N);
        k_gemm_mfma<<<gemmBlocks, 512, GEMM_LDS_BYTES, stream>>>(
            aggh, wtHi + l * 16384, wtLo + l * 16384, bs[l],
            (l < 4) ? dis : nullptr, hout, ntiles, N,
            (l == 4) ? invn : nullptr);
        const __half* t = hin; hin = hout; hout = (__half*)t;
    }
    // after loop: hin = h5 (hB), hout = hA
    k_agnn<<<aggBlocks, 256, 0, stream>>>(hin, csr, offs, invn, beta1, hout, N, invn2);
    k_agnn<<<aggBlocks, 256, 0, stream>>>(hout, csr, offs, invn2, beta2, (__half*)hin, N, nullptr);
    k_pool<<<(G + 15) / 16, 256, 0, stream>>>(hin, gst, Wl, bl, out, G);
}